// Round 1
// baseline (1043.820 us; speedup 1.0000x reference)
//
#include <hip/hip_runtime.h>
#include <math.h>

#define B_   4
#define T_   20000
#define SUB  20
#define ENO  2000
#define INO  500
#define HID  10
#define NCOS 24
#define TNO  200

// ---------------- prep 1: softmax over subunit axis + Cw = C * exp(scale), e2 = exp(W2)
__global__ __launch_bounds__(256) void prep1_kernel(
    const float* __restrict__ Ce_raw, const float* __restrict__ Ci_raw,
    const float* __restrict__ ge, const float* __restrict__ gi,
    const float* __restrict__ Es, const float* __restrict__ Is,
    const float* __restrict__ W2, const int* __restrict__ testp,
    float* __restrict__ outCe, float* __restrict__ outCi,
    float* __restrict__ CwE, float* __restrict__ CwI, float* __restrict__ e2)
{
  int idx = blockIdx.x * 256 + threadIdx.x;
  int test = *testp;
  float scale = test ? 10000.f : 1000.f;
  if (idx < ENO + INO) {
    const float* raw; const float* g; float* outC; float* Cw; int n, col; float sc;
    if (idx < ENO) { raw = Ce_raw; g = ge; outC = outCe; Cw = CwE; n = ENO; col = idx;      sc = expf(Es[col]); }
    else           { raw = Ci_raw; g = gi; outC = outCi; Cw = CwI; n = INO; col = idx - ENO; sc = expf(Is[col]); }
    float v[SUB]; float m = -1e30f;
    #pragma unroll
    for (int s = 0; s < SUB; s++) {
      float x = raw[s * n + col];
      if (!test) x += g[s * n + col];
      x *= scale;
      v[s] = x; m = fmaxf(m, x);
    }
    float sum = 0.f;
    #pragma unroll
    for (int s = 0; s < SUB; s++) { v[s] = expf(v[s] - m); sum += v[s]; }
    float inv = 1.f / sum;
    #pragma unroll
    for (int s = 0; s < SUB; s++) { float c = v[s] * inv; outC[s * n + col] = c; Cw[s * n + col] = c * sc; }
  } else if (idx < ENO + INO + SUB * HID) {
    int j = idx - (ENO + INO);
    e2[j] = expf(W2[j]);
  }
}

// ---------------- prep 2: effective kernels Keff[src][s][h][d] = sum_k W[s*HID+h,k] * basis(k,d)
__global__ __launch_bounds__(256) void prep2_kernel(
    const float* __restrict__ We, const float* __restrict__ Wi, float* __restrict__ Keff)
{
  int idx = blockIdx.x * 256 + threadIdx.x;
  if (idx >= 2 * SUB * HID * TNO) return;
  int d   = idx % TNO;
  int sh  = (idx / TNO) % (SUB * HID);
  int src = idx / (TNO * SUB * HID);
  const float* W = src ? Wi : We;           // [SUB*HID][NCOS]
  const float PIF = 3.14159265358979323846f;
  float raw = 6.0f * logf((float)d + 1.0f + 1e-7f);
  float acc = 0.f;
  #pragma unroll
  for (int k = 0; k < NCOS; k++) {
    float ph = 1.57079632679489662f * (float)k;
    if (raw >= ph - PIF && raw <= ph + PIF) {
      acc += W[sh * NCOS + k] * (0.5f * __cosf(raw - ph) * 0.f + 0.5f * cosf(raw - ph) + 0.5f);
    }
  }
  Keff[idx] = acc;
}

// ---------------- GEMM: syn[b][s][t] = sum_e S[b,t,e] * Cw[s,e]
// tile: 256 t-rows x all 20 s; chunks of 32 e. LDS stride 36 floats (conflict-free b128).
__global__ __launch_bounds__(256, 4) void gemm_syn_kernel(
    const float* __restrict__ S_e, const float* __restrict__ S_i,
    const float* __restrict__ CwE, const float* __restrict__ CwI,
    float* __restrict__ synE, float* __restrict__ synI)
{
  const int b  = blockIdx.y;
  const int zi = blockIdx.z;
  const float* __restrict__ S  = zi ? S_i : S_e;
  const float* __restrict__ Cw = zi ? CwI : CwE;
  float* __restrict__ syn      = zi ? synI : synE;
  const int n = zi ? INO : ENO;
  const int t0 = blockIdx.x * 256;

  __shared__ __align__(16) float sS[256 * 36];
  __shared__ __align__(16) float sC[SUB * 32];

  const int tid = threadIdx.x;
  const int l = tid & 63;
  const int w = tid >> 6;
  const int s0 = w * 5;

  float acc[4][5] = {};
  const int nc = (n + 31) / 32;
  const long rowbase = (long)b * T_;

  for (int c = 0; c < nc; c++) {
    int e0 = c * 32;
    // stage S tile [256][32]
    #pragma unroll
    for (int p = 0; p < 8; p++) {
      int idx = tid + p * 256;
      int row = idx >> 3;
      int c4  = idx & 7;
      int e = e0 + c4 * 4;
      int t = t0 + row;
      float4 val = make_float4(0.f, 0.f, 0.f, 0.f);
      if (t < T_ && e < n) val = *(const float4*)&S[(rowbase + t) * n + e];
      *(float4*)&sS[row * 36 + c4 * 4] = val;
    }
    // stage Cw tile [20][32]
    if (tid < 160) {
      int s = tid >> 3, c4 = tid & 7;
      int e = e0 + c4 * 4;
      float4 v = make_float4(0.f, 0.f, 0.f, 0.f);
      if (e < n) v = *(const float4*)&Cw[s * n + e];
      *(float4*)&sC[s * 32 + c4 * 4] = v;
    }
    __syncthreads();
    #pragma unroll
    for (int e4 = 0; e4 < 8; e4++) {
      float4 cw[5];
      #pragma unroll
      for (int j = 0; j < 5; j++) cw[j] = *(float4*)&sC[(s0 + j) * 32 + e4 * 4];
      #pragma unroll
      for (int k = 0; k < 4; k++) {
        float4 sv = *(float4*)&sS[(l + 64 * k) * 36 + e4 * 4];
        #pragma unroll
        for (int j = 0; j < 5; j++) {
          acc[k][j] += sv.x * cw[j].x;
          acc[k][j] += sv.y * cw[j].y;
          acc[k][j] += sv.z * cw[j].z;
          acc[k][j] += sv.w * cw[j].w;
        }
      }
    }
    __syncthreads();
  }
  #pragma unroll
  for (int k = 0; k < 4; k++) {
    int t = t0 + l + 64 * k;
    if (t < T_) {
      #pragma unroll
      for (int j = 0; j < 5; j++)
        syn[((long)b * SUB + s0 + j) * T_ + t] = acc[k][j];
    }
  }
}

// ---------------- conv: pre[h,t] = sum_d Ke[h,d]*syn_e[t-d] + Ki[h,d]*syn_i[t-d]; tanh; combine over h
// block = (chunk of 1000 t, s, b); 250 active threads x 4 t each
__global__ __launch_bounds__(256, 2) void conv_kernel(
    const float* __restrict__ synE, const float* __restrict__ synI,
    const float* __restrict__ Keff, const float* __restrict__ e2,
    const float* __restrict__ b1, float* __restrict__ sub_bst)
{
  const int chunk = blockIdx.x;       // 0..19
  const int s = blockIdx.y;
  const int b = blockIdx.z;
  const int cs = chunk * 1000;

  __shared__ __align__(16) float se[1200];
  __shared__ __align__(16) float si[1200];
  __shared__ __align__(16) float te[HID * TNO];
  __shared__ __align__(16) float ti[HID * TNO];
  __shared__ float se2[HID], sb[HID];

  const int tid = threadIdx.x;
  const float* __restrict__ pe = &synE[((long)b * SUB + s) * T_];
  const float* __restrict__ pin = &synI[((long)b * SUB + s) * T_];

  for (int i4 = tid; i4 < 300; i4 += 256) {
    int gt = cs - 200 + i4 * 4;
    float4 ve = make_float4(0.f, 0.f, 0.f, 0.f);
    float4 vi = make_float4(0.f, 0.f, 0.f, 0.f);
    if (gt >= 0) { ve = *(const float4*)&pe[gt]; vi = *(const float4*)&pin[gt]; }
    *(float4*)&se[i4 * 4] = ve;
    *(float4*)&si[i4 * 4] = vi;
  }
  const float* __restrict__ ke = &Keff[(long)s * HID * TNO];
  const float* __restrict__ ki = &Keff[((long)SUB + s) * HID * TNO];
  for (int i4 = tid; i4 < 500; i4 += 256) {
    *(float4*)&te[i4 * 4] = *(const float4*)&ke[i4 * 4];
    *(float4*)&ti[i4 * 4] = *(const float4*)&ki[i4 * 4];
  }
  if (tid < HID) { se2[tid] = e2[s * HID + tid]; sb[tid] = b1[s * HID + tid]; }
  __syncthreads();

  if (tid >= 250) return;
  const int lofs = 200 + 4 * tid;   // LDS index of this thread's t0
  float so[4] = {0.f, 0.f, 0.f, 0.f};

  #pragma unroll
  for (int half = 0; half < 2; half++) {
    const int h0 = half * 5;
    float acc[5][4] = {};
    float we[8], wi[8];
    *(float4*)&we[4] = *(float4*)&se[lofs];
    *(float4*)&wi[4] = *(float4*)&si[lofs];
    for (int dstep = 0; dstep < 50; dstep++) {
      const int d0 = dstep * 4;
      *(float4*)&we[0] = *(float4*)&se[lofs - d0 - 4];
      *(float4*)&wi[0] = *(float4*)&si[lofs - d0 - 4];
      float4 tpe[5], tpi[5];
      #pragma unroll
      for (int h = 0; h < 5; h++) {
        tpe[h] = *(float4*)&te[(h0 + h) * TNO + d0];
        tpi[h] = *(float4*)&ti[(h0 + h) * TNO + d0];
      }
      #pragma unroll
      for (int dd = 0; dd < 4; dd++) {
        #pragma unroll
        for (int h = 0; h < 5; h++) {
          float tapeh = ((float*)&tpe[h])[dd];
          float tapih = ((float*)&tpi[h])[dd];
          #pragma unroll
          for (int j = 0; j < 4; j++) {
            acc[h][j] += tapeh * we[4 + j - dd];
            acc[h][j] += tapih * wi[4 + j - dd];
          }
        }
      }
      #pragma unroll
      for (int m = 0; m < 4; m++) { we[4 + m] = we[m]; wi[4 + m] = wi[m]; }
    }
    #pragma unroll
    for (int h = 0; h < 5; h++) {
      float eh = se2[h0 + h], bh = sb[h0 + h];
      #pragma unroll
      for (int j = 0; j < 4; j++) so[j] += eh * tanhf(acc[h][j] + bh);
    }
  }
  int t0 = cs + 4 * tid;
  *(float4*)&sub_bst[((long)b * SUB + s) * T_ + t0] = *(float4*)&so[0];
}

// ---------------- final: transpose sub_bst[b][s][t] -> sub_out[b][t][s], final[b][t] = sum_s + V_o
__global__ __launch_bounds__(256) void final_kernel(
    const float* __restrict__ sub_bst, const float* __restrict__ Vo,
    float* __restrict__ out_final, float* __restrict__ out_sub)
{
  int t = blockIdx.x * 256 + threadIdx.x;
  int b = blockIdx.y;
  if (t >= T_) return;
  float vo = Vo[0];
  float sum = 0.f;
  #pragma unroll
  for (int s = 0; s < SUB; s++) {
    float v = sub_bst[((long)b * SUB + s) * T_ + t];
    sum += v;
    out_sub[(((long)b * T_) + t) * SUB + s] = v;
  }
  out_final[(long)b * T_ + t] = sum + vo;
}

extern "C" void kernel_launch(void* const* d_in, const int* in_sizes, int n_in,
                              void* d_out, int out_size, void* d_ws, size_t ws_size,
                              hipStream_t stream)
{
  const float* S_e    = (const float*)d_in[0];
  const float* S_i    = (const float*)d_in[1];
  const int*   testp  = (const int*)d_in[3];
  const float* g_e    = (const float*)d_in[4];
  const float* g_i    = (const float*)d_in[5];
  const float* Es     = (const float*)d_in[6];
  const float* Is     = (const float*)d_in[7];
  const float* We     = (const float*)d_in[8];
  const float* Wi     = (const float*)d_in[9];
  const float* W2     = (const float*)d_in[10];
  const float* b1     = (const float*)d_in[11];
  const float* Ce_raw = (const float*)d_in[12];
  const float* Ci_raw = (const float*)d_in[13];
  const float* Vo     = (const float*)d_in[14];

  float* ws   = (float*)d_ws;
  float* CwE  = ws;                      // 40000
  float* CwI  = ws + 40000;              // 10000
  float* Keff = ws + 50000;              // 80000
  float* e2   = ws + 130000;             // 200
  float* synE = ws + 130200;             // 1,600,000
  float* synI = synE + 1600000;          // 1,600,000
  float* subb = synI + 1600000;          // 1,600,000

  float* out     = (float*)d_out;
  float* o_final = out;                  // 80,000
  float* o_sub   = out + 80000;          // 1,600,000
  float* o_Ce    = out + 1680000;        // 40,000
  float* o_Ci    = out + 1720000;        // 10,000

  prep1_kernel<<<11, 256, 0, stream>>>(Ce_raw, Ci_raw, g_e, g_i, Es, Is, W2, testp,
                                       o_Ce, o_Ci, CwE, CwI, e2);
  prep2_kernel<<<(2 * SUB * HID * TNO + 255) / 256, 256, 0, stream>>>(We, Wi, Keff);
  gemm_syn_kernel<<<dim3((T_ + 255) / 256, B_, 2), 256, 0, stream>>>(S_e, S_i, CwE, CwI, synE, synI);
  conv_kernel<<<dim3(20, SUB, B_), 256, 0, stream>>>(synE, synI, Keff, e2, b1, subb);
  final_kernel<<<dim3((T_ + 255) / 256, B_), 256, 0, stream>>>(subb, Vo, o_final, o_sub);
}

// Round 2
// 1023.502 us; speedup vs baseline: 1.0199x; 1.0199x over previous
//
#include <hip/hip_runtime.h>
#include <math.h>

#define B_   4
#define T_   20000
#define SUB  20
#define ENO  2000
#define INO  500
#define HID  10
#define NCOS 24
#define TNO  200

// ---------------- prep 1: softmax over subunit axis + Cw = C * exp(scale), e2 = exp(W2)
__global__ __launch_bounds__(256) void prep1_kernel(
    const float* __restrict__ Ce_raw, const float* __restrict__ Ci_raw,
    const float* __restrict__ ge, const float* __restrict__ gi,
    const float* __restrict__ Es, const float* __restrict__ Is,
    const float* __restrict__ W2, const int* __restrict__ testp,
    float* __restrict__ outCe, float* __restrict__ outCi,
    float* __restrict__ CwE, float* __restrict__ CwI, float* __restrict__ e2)
{
  int idx = blockIdx.x * 256 + threadIdx.x;
  int test = *testp;
  float scale = test ? 10000.f : 1000.f;
  if (idx < ENO + INO) {
    const float* raw; const float* g; float* outC; float* Cw; int n, col; float sc;
    if (idx < ENO) { raw = Ce_raw; g = ge; outC = outCe; Cw = CwE; n = ENO; col = idx;      sc = expf(Es[col]); }
    else           { raw = Ci_raw; g = gi; outC = outCi; Cw = CwI; n = INO; col = idx - ENO; sc = expf(Is[col]); }
    float v[SUB]; float m = -1e30f;
    #pragma unroll
    for (int s = 0; s < SUB; s++) {
      float x = raw[s * n + col];
      if (!test) x += g[s * n + col];
      x *= scale;
      v[s] = x; m = fmaxf(m, x);
    }
    float sum = 0.f;
    #pragma unroll
    for (int s = 0; s < SUB; s++) { v[s] = expf(v[s] - m); sum += v[s]; }
    float inv = 1.f / sum;
    #pragma unroll
    for (int s = 0; s < SUB; s++) { float c = v[s] * inv; outC[s * n + col] = c; Cw[s * n + col] = c * sc; }
  } else if (idx < ENO + INO + SUB * HID) {
    int j = idx - (ENO + INO);
    e2[j] = expf(W2[j]);
  }
}

// ---------------- prep 2: effective kernels Keff[src][s][h][d] = sum_k W[s*HID+h,k] * basis(k,d)
__global__ __launch_bounds__(256) void prep2_kernel(
    const float* __restrict__ We, const float* __restrict__ Wi, float* __restrict__ Keff)
{
  int idx = blockIdx.x * 256 + threadIdx.x;
  if (idx >= 2 * SUB * HID * TNO) return;
  int d   = idx % TNO;
  int sh  = (idx / TNO) % (SUB * HID);
  int src = idx / (TNO * SUB * HID);
  const float* W = src ? Wi : We;           // [SUB*HID][NCOS]
  const float PIF = 3.14159265358979323846f;
  float raw = 6.0f * logf((float)d + 1.0f + 1e-7f);
  float acc = 0.f;
  #pragma unroll
  for (int k = 0; k < NCOS; k++) {
    float ph = 1.57079632679489662f * (float)k;
    if (raw >= ph - PIF && raw <= ph + PIF) {
      acc += W[sh * NCOS + k] * (0.5f * cosf(raw - ph) + 0.5f);
    }
  }
  Keff[idx] = acc;
}

// ---------------- GEMM: syn[b][s][t] = sum_e S[b,t,e] * Cw[s,e]
// t-tile 128, K split into 500-wide slices (z=0..3 -> E quarters via atomicAdd, z=4 -> I store).
// Register-prefetch double buffer: load chunk c+1 to regs while computing chunk c.
__global__ __launch_bounds__(256, 6) void gemm_syn_kernel(
    const float* __restrict__ S_e, const float* __restrict__ S_i,
    const float* __restrict__ CwE, const float* __restrict__ CwI,
    float* __restrict__ synE, float* __restrict__ synI)
{
  const int b  = blockIdx.y;
  const int z  = blockIdx.z;            // 0..3: E slices, 4: I
  const bool isE = (z < 4);
  const float* __restrict__ S  = isE ? S_e : S_i;
  const float* __restrict__ Cw = isE ? CwE : CwI;
  const int n      = isE ? ENO : INO;
  const int estart = isE ? z * 500 : 0;
  const int eend   = estart + 500;
  const int t0 = blockIdx.x * 128;

  __shared__ __align__(16) float sS[128 * 36];   // pad 36: strided b128 reads conflict-free
  __shared__ __align__(16) float sC[SUB * 32];

  const int tid = threadIdx.x;
  const int l  = tid & 63;
  const int w  = tid >> 6;
  const int s0 = w * 5;
  const int rr = tid >> 3;              // staging row base (0..31)
  const int c4 = tid & 7;               // staging float4 column
  const long rowbase = (long)b * T_;

  float acc[2][5] = {};
  float4 pS[4];
  float4 pC;

  // prefetch chunk 0
  {
    int ebase = estart;
    int e = ebase + c4 * 4;
    #pragma unroll
    for (int p = 0; p < 4; p++) {
      int t = t0 + rr + 32 * p;
      pS[p] = make_float4(0.f, 0.f, 0.f, 0.f);
      if (t < T_ && e < eend) pS[p] = *(const float4*)&S[(rowbase + t) * n + e];
    }
    pC = make_float4(0.f, 0.f, 0.f, 0.f);
    if (tid < 160 && e < eend) pC = *(const float4*)&Cw[rr * n + e];
  }

  for (int c = 0; c < 16; c++) {
    // commit prefetched chunk to LDS
    #pragma unroll
    for (int p = 0; p < 4; p++)
      *(float4*)&sS[(rr + 32 * p) * 36 + c4 * 4] = pS[p];
    if (tid < 160)
      *(float4*)&sC[rr * 32 + c4 * 4] = pC;

    // issue prefetch for next chunk (completes during compute)
    if (c + 1 < 16) {
      int ebase = estart + (c + 1) * 32;
      int e = ebase + c4 * 4;
      #pragma unroll
      for (int p = 0; p < 4; p++) {
        int t = t0 + rr + 32 * p;
        pS[p] = make_float4(0.f, 0.f, 0.f, 0.f);
        if (t < T_ && e < eend) pS[p] = *(const float4*)&S[(rowbase + t) * n + e];
      }
      pC = make_float4(0.f, 0.f, 0.f, 0.f);
      if (tid < 160 && e < eend) pC = *(const float4*)&Cw[rr * n + e];
    }

    __syncthreads();
    #pragma unroll
    for (int e4 = 0; e4 < 8; e4++) {
      float4 cw[5];
      #pragma unroll
      for (int j = 0; j < 5; j++) cw[j] = *(float4*)&sC[(s0 + j) * 32 + e4 * 4];
      #pragma unroll
      for (int k = 0; k < 2; k++) {
        float4 sv = *(float4*)&sS[(l + 64 * k) * 36 + e4 * 4];
        #pragma unroll
        for (int j = 0; j < 5; j++) {
          acc[k][j] += sv.x * cw[j].x;
          acc[k][j] += sv.y * cw[j].y;
          acc[k][j] += sv.z * cw[j].z;
          acc[k][j] += sv.w * cw[j].w;
        }
      }
    }
    __syncthreads();
  }

  if (isE) {
    #pragma unroll
    for (int k = 0; k < 2; k++) {
      int t = t0 + l + 64 * k;
      if (t < T_) {
        #pragma unroll
        for (int j = 0; j < 5; j++)
          atomicAdd(&synE[((long)b * SUB + s0 + j) * T_ + t], acc[k][j]);
      }
    }
  } else {
    #pragma unroll
    for (int k = 0; k < 2; k++) {
      int t = t0 + l + 64 * k;
      if (t < T_) {
        #pragma unroll
        for (int j = 0; j < 5; j++)
          synI[((long)b * SUB + s0 + j) * T_ + t] = acc[k][j];
      }
    }
  }
}

// ---------------- conv: pre[h,t] = sum_d Ke[h,d]*syn_e[t-d] + Ki[h,d]*syn_i[t-d]; tanh; combine over h
__global__ __launch_bounds__(256, 2) void conv_kernel(
    const float* __restrict__ synE, const float* __restrict__ synI,
    const float* __restrict__ Keff, const float* __restrict__ e2,
    const float* __restrict__ b1, float* __restrict__ sub_bst)
{
  const int chunk = blockIdx.x;       // 0..19
  const int s = blockIdx.y;
  const int b = blockIdx.z;
  const int cs = chunk * 1000;

  __shared__ __align__(16) float se[1200];
  __shared__ __align__(16) float si[1200];
  __shared__ __align__(16) float te[HID * TNO];
  __shared__ __align__(16) float ti[HID * TNO];
  __shared__ float se2[HID], sb[HID];

  const int tid = threadIdx.x;
  const float* __restrict__ pe = &synE[((long)b * SUB + s) * T_];
  const float* __restrict__ pin = &synI[((long)b * SUB + s) * T_];

  for (int i4 = tid; i4 < 300; i4 += 256) {
    int gt = cs - 200 + i4 * 4;
    float4 ve = make_float4(0.f, 0.f, 0.f, 0.f);
    float4 vi = make_float4(0.f, 0.f, 0.f, 0.f);
    if (gt >= 0) { ve = *(const float4*)&pe[gt]; vi = *(const float4*)&pin[gt]; }
    *(float4*)&se[i4 * 4] = ve;
    *(float4*)&si[i4 * 4] = vi;
  }
  const float* __restrict__ ke = &Keff[(long)s * HID * TNO];
  const float* __restrict__ ki = &Keff[((long)SUB + s) * HID * TNO];
  for (int i4 = tid; i4 < 500; i4 += 256) {
    *(float4*)&te[i4 * 4] = *(const float4*)&ke[i4 * 4];
    *(float4*)&ti[i4 * 4] = *(const float4*)&ki[i4 * 4];
  }
  if (tid < HID) { se2[tid] = e2[s * HID + tid]; sb[tid] = b1[s * HID + tid]; }
  __syncthreads();

  if (tid >= 250) return;
  const int lofs = 200 + 4 * tid;
  float so[4] = {0.f, 0.f, 0.f, 0.f};

  #pragma unroll
  for (int half = 0; half < 2; half++) {
    const int h0 = half * 5;
    float acc[5][4] = {};
    float we[8], wi[8];
    *(float4*)&we[4] = *(float4*)&se[lofs];
    *(float4*)&wi[4] = *(float4*)&si[lofs];
    for (int dstep = 0; dstep < 50; dstep++) {
      const int d0 = dstep * 4;
      *(float4*)&we[0] = *(float4*)&se[lofs - d0 - 4];
      *(float4*)&wi[0] = *(float4*)&si[lofs - d0 - 4];
      float4 tpe[5], tpi[5];
      #pragma unroll
      for (int h = 0; h < 5; h++) {
        tpe[h] = *(float4*)&te[(h0 + h) * TNO + d0];
        tpi[h] = *(float4*)&ti[(h0 + h) * TNO + d0];
      }
      #pragma unroll
      for (int dd = 0; dd < 4; dd++) {
        #pragma unroll
        for (int h = 0; h < 5; h++) {
          float tapeh = ((float*)&tpe[h])[dd];
          float tapih = ((float*)&tpi[h])[dd];
          #pragma unroll
          for (int j = 0; j < 4; j++) {
            acc[h][j] += tapeh * we[4 + j - dd];
            acc[h][j] += tapih * wi[4 + j - dd];
          }
        }
      }
      #pragma unroll
      for (int m = 0; m < 4; m++) { we[4 + m] = we[m]; wi[4 + m] = wi[m]; }
    }
    #pragma unroll
    for (int h = 0; h < 5; h++) {
      float eh = se2[h0 + h], bh = sb[h0 + h];
      #pragma unroll
      for (int j = 0; j < 4; j++) so[j] += eh * tanhf(acc[h][j] + bh);
    }
  }
  int t0 = cs + 4 * tid;
  *(float4*)&sub_bst[((long)b * SUB + s) * T_ + t0] = *(float4*)&so[0];
}

// ---------------- final: transpose sub_bst[b][s][t] -> sub_out[b][t][s], final[b][t] = sum_s + V_o
__global__ __launch_bounds__(256) void final_kernel(
    const float* __restrict__ sub_bst, const float* __restrict__ Vo,
    float* __restrict__ out_final, float* __restrict__ out_sub)
{
  int t = blockIdx.x * 256 + threadIdx.x;
  int b = blockIdx.y;
  if (t >= T_) return;
  float vo = Vo[0];
  float sum = 0.f;
  #pragma unroll
  for (int s = 0; s < SUB; s++) {
    float v = sub_bst[((long)b * SUB + s) * T_ + t];
    sum += v;
    out_sub[(((long)b * T_) + t) * SUB + s] = v;
  }
  out_final[(long)b * T_ + t] = sum + vo;
}

extern "C" void kernel_launch(void* const* d_in, const int* in_sizes, int n_in,
                              void* d_out, int out_size, void* d_ws, size_t ws_size,
                              hipStream_t stream)
{
  const float* S_e    = (const float*)d_in[0];
  const float* S_i    = (const float*)d_in[1];
  const int*   testp  = (const int*)d_in[3];
  const float* g_e    = (const float*)d_in[4];
  const float* g_i    = (const float*)d_in[5];
  const float* Es     = (const float*)d_in[6];
  const float* Is     = (const float*)d_in[7];
  const float* We     = (const float*)d_in[8];
  const float* Wi     = (const float*)d_in[9];
  const float* W2     = (const float*)d_in[10];
  const float* b1     = (const float*)d_in[11];
  const float* Ce_raw = (const float*)d_in[12];
  const float* Ci_raw = (const float*)d_in[13];
  const float* Vo     = (const float*)d_in[14];

  float* ws   = (float*)d_ws;
  float* CwE  = ws;                      // 40000
  float* CwI  = ws + 40000;              // 10000
  float* Keff = ws + 50000;              // 80000
  float* e2   = ws + 130000;             // 200
  float* synE = ws + 130200;             // 1,600,000
  float* synI = synE + 1600000;          // 1,600,000
  float* subb = synI + 1600000;          // 1,600,000

  float* out     = (float*)d_out;
  float* o_final = out;                  // 80,000
  float* o_sub   = out + 80000;          // 1,600,000
  float* o_Ce    = out + 1680000;        // 40,000
  float* o_Ci    = out + 1720000;        // 10,000

  prep1_kernel<<<11, 256, 0, stream>>>(Ce_raw, Ci_raw, g_e, g_i, Es, Is, W2, testp,
                                       o_Ce, o_Ci, CwE, CwI, e2);
  prep2_kernel<<<(2 * SUB * HID * TNO + 255) / 256, 256, 0, stream>>>(We, Wi, Keff);
  hipMemsetAsync(synE, 0, (size_t)1600000 * sizeof(float), stream);
  gemm_syn_kernel<<<dim3((T_ + 127) / 128, B_, 5), 256, 0, stream>>>(S_e, S_i, CwE, CwI, synE, synI);
  conv_kernel<<<dim3(20, SUB, B_), 256, 0, stream>>>(synE, synI, Keff, e2, b1, subb);
  final_kernel<<<dim3((T_ + 255) / 256, B_), 256, 0, stream>>>(subb, Vo, o_final, o_sub);
}

// Round 3
// 739.976 us; speedup vs baseline: 1.4106x; 1.3832x over previous
//
#include <hip/hip_runtime.h>
#include <math.h>

#define B_   4
#define T_   20000
#define SUB  20
#define ENO  2000
#define INO  500
#define HID  10
#define NCOS 24
#define TNO  200

// ---------------- prep 1: softmax over subunit axis + Cw = C * exp(scale), e2 = exp(W2)
__global__ __launch_bounds__(256) void prep1_kernel(
    const float* __restrict__ Ce_raw, const float* __restrict__ Ci_raw,
    const float* __restrict__ ge, const float* __restrict__ gi,
    const float* __restrict__ Es, const float* __restrict__ Is,
    const float* __restrict__ W2, const int* __restrict__ testp,
    float* __restrict__ outCe, float* __restrict__ outCi,
    float* __restrict__ CwE, float* __restrict__ CwI, float* __restrict__ e2)
{
  int idx = blockIdx.x * 256 + threadIdx.x;
  int test = *testp;
  float scale = test ? 10000.f : 1000.f;
  if (idx < ENO + INO) {
    const float* raw; const float* g; float* outC; float* Cw; int n, col; float sc;
    if (idx < ENO) { raw = Ce_raw; g = ge; outC = outCe; Cw = CwE; n = ENO; col = idx;      sc = expf(Es[col]); }
    else           { raw = Ci_raw; g = gi; outC = outCi; Cw = CwI; n = INO; col = idx - ENO; sc = expf(Is[col]); }
    float v[SUB]; float m = -1e30f;
    #pragma unroll
    for (int s = 0; s < SUB; s++) {
      float x = raw[s * n + col];
      if (!test) x += g[s * n + col];
      x *= scale;
      v[s] = x; m = fmaxf(m, x);
    }
    float sum = 0.f;
    #pragma unroll
    for (int s = 0; s < SUB; s++) { v[s] = expf(v[s] - m); sum += v[s]; }
    float inv = 1.f / sum;
    #pragma unroll
    for (int s = 0; s < SUB; s++) { float c = v[s] * inv; outC[s * n + col] = c; Cw[s * n + col] = c * sc; }
  } else if (idx < ENO + INO + SUB * HID) {
    int j = idx - (ENO + INO);
    e2[j] = expf(W2[j]);
  }
}

// ---------------- prep 2: effective kernels Keff[src][s][h][d] = sum_k W[s*HID+h,k] * basis(k,d)
__global__ __launch_bounds__(256) void prep2_kernel(
    const float* __restrict__ We, const float* __restrict__ Wi, float* __restrict__ Keff)
{
  int idx = blockIdx.x * 256 + threadIdx.x;
  if (idx >= 2 * SUB * HID * TNO) return;
  int d   = idx % TNO;
  int sh  = (idx / TNO) % (SUB * HID);
  int src = idx / (TNO * SUB * HID);
  const float* W = src ? Wi : We;           // [SUB*HID][NCOS]
  const float PIF = 3.14159265358979323846f;
  float raw = 6.0f * logf((float)d + 1.0f + 1e-7f);
  float acc = 0.f;
  #pragma unroll
  for (int k = 0; k < NCOS; k++) {
    float ph = 1.57079632679489662f * (float)k;
    if (raw >= ph - PIF && raw <= ph + PIF) {
      acc += W[sh * NCOS + k] * (0.5f * cosf(raw - ph) + 0.5f);
    }
  }
  Keff[idx] = acc;
}

// ---------------- GEMM: syn[b][s][t] = sum_e S[b,t,e] * Cw[s,e]
// Block = 16 t-rows x full K. z-loop over five 500-e slices (4 E + 1 I).
// S staged as CONTIGUOUS 2000B row-runs (no 128B strided pieces -> no L2 overfetch).
// Thread: 8 rows x 5 s; lane: tg=l&1 (row parity), ep=l>>1 (32-way e-split).
// Butterfly shfl_xor reduce over ep at the end of E (z=3) and I (z=4).
__global__ __launch_bounds__(256, 2) void gemm_syn_kernel(
    const float* __restrict__ S_e, const float* __restrict__ S_i,
    const float* __restrict__ CwE, const float* __restrict__ CwI,
    float* __restrict__ synE, float* __restrict__ synI)
{
  const int b  = blockIdx.y;
  const int t0 = blockIdx.x * 16;

  __shared__ __align__(16) float sS[16 * 528];    // stride 528 -> 2-way banks (free)
  __shared__ __align__(16) float sCw[20 * 512];   // broadcast reads (free)

  const int tid = threadIdx.x;
  const int l   = tid & 63;
  const int w   = tid >> 6;
  const int s0  = w * 5;
  const int tg  = l & 1;
  const int ep  = l >> 1;

  // zero the e-pad columns [500,512) once; staging never writes them
  if (tid < 192)            { int r = tid / 12, c = tid % 12;            sS[r * 528 + 500 + c] = 0.f; }
  else if (tid < 432)       { int u = tid - 192; int s = u / 12, c = u % 12; sCw[s * 512 + 500 + c] = 0.f; }

  float acc[8][5] = {};

  for (int z = 0; z < 5; z++) {
    const bool isE = (z < 4);
    // ---- stage S: 16 rows x 500 floats, each row a contiguous 2000B run
    {
      const float* __restrict__ src = isE ? (S_e + ((long)(b * T_ + t0)) * ENO + z * 500)
                                          : (S_i + ((long)(b * T_ + t0)) * INO);
      const int rs = isE ? ENO : INO;
      for (int u = tid; u < 2000; u += 256) {
        int r = u / 125, k = u - r * 125;
        float4 v = *(const float4*)&src[(long)r * rs + 4 * k];
        *(float4*)&sS[r * 528 + 4 * k] = v;
      }
      const float* __restrict__ csrc = isE ? (CwE + z * 500) : CwI;
      const int cs2 = isE ? ENO : INO;
      for (int u = tid; u < 2500; u += 256) {
        int s = u / 125, k = u - s * 125;
        float4 v = *(const float4*)&csrc[(long)s * cs2 + 4 * k];
        *(float4*)&sCw[s * 512 + 4 * k] = v;
      }
    }
    __syncthreads();

    #pragma unroll
    for (int step = 0; step < 4; step++) {
      const int e = 4 * ep + 128 * step;
      float4 cw[5];
      #pragma unroll
      for (int j = 0; j < 5; j++) cw[j] = *(float4*)&sCw[(s0 + j) * 512 + e];
      #pragma unroll
      for (int tt = 0; tt < 8; tt++) {
        float4 sv = *(float4*)&sS[(tg + 2 * tt) * 528 + e];
        #pragma unroll
        for (int j = 0; j < 5; j++) {
          acc[tt][j] += sv.x * cw[j].x;
          acc[tt][j] += sv.y * cw[j].y;
          acc[tt][j] += sv.z * cw[j].z;
          acc[tt][j] += sv.w * cw[j].w;
        }
      }
    }
    __syncthreads();   // before next z overwrites LDS

    if (z == 3 || z == 4) {
      // reduce over ep (lane bits 1..5)
      #pragma unroll
      for (int mask = 2; mask <= 32; mask <<= 1) {
        #pragma unroll
        for (int tt = 0; tt < 8; tt++)
          #pragma unroll
          for (int j = 0; j < 5; j++)
            acc[tt][j] += __shfl_xor(acc[tt][j], mask, 64);
      }
      float* __restrict__ dst = (z == 3) ? synE : synI;
      if (l < 2) {
        #pragma unroll
        for (int j = 0; j < 5; j++)
          #pragma unroll
          for (int tt = 0; tt < 8; tt++)
            dst[((long)b * SUB + s0 + j) * T_ + t0 + tg + 2 * tt] = acc[tt][j];
      }
      #pragma unroll
      for (int tt = 0; tt < 8; tt++)
        #pragma unroll
        for (int j = 0; j < 5; j++) acc[tt][j] = 0.f;
    }
  }
}

// ---------------- conv: pre[h,t] = sum_d Ke[h,d]*syn_e[t-d] + Ki[h,d]*syn_i[t-d]; tanh; combine over h
__global__ __launch_bounds__(256, 2) void conv_kernel(
    const float* __restrict__ synE, const float* __restrict__ synI,
    const float* __restrict__ Keff, const float* __restrict__ e2,
    const float* __restrict__ b1, float* __restrict__ sub_bst)
{
  const int chunk = blockIdx.x;       // 0..19
  const int s = blockIdx.y;
  const int b = blockIdx.z;
  const int cs = chunk * 1000;

  __shared__ __align__(16) float se[1200];
  __shared__ __align__(16) float si[1200];
  __shared__ __align__(16) float te[HID * TNO];
  __shared__ __align__(16) float ti[HID * TNO];
  __shared__ float se2[HID], sb[HID];

  const int tid = threadIdx.x;
  const float* __restrict__ pe = &synE[((long)b * SUB + s) * T_];
  const float* __restrict__ pin = &synI[((long)b * SUB + s) * T_];

  for (int i4 = tid; i4 < 300; i4 += 256) {
    int gt = cs - 200 + i4 * 4;
    float4 ve = make_float4(0.f, 0.f, 0.f, 0.f);
    float4 vi = make_float4(0.f, 0.f, 0.f, 0.f);
    if (gt >= 0) { ve = *(const float4*)&pe[gt]; vi = *(const float4*)&pin[gt]; }
    *(float4*)&se[i4 * 4] = ve;
    *(float4*)&si[i4 * 4] = vi;
  }
  const float* __restrict__ ke = &Keff[(long)s * HID * TNO];
  const float* __restrict__ ki = &Keff[((long)SUB + s) * HID * TNO];
  for (int i4 = tid; i4 < 500; i4 += 256) {
    *(float4*)&te[i4 * 4] = *(const float4*)&ke[i4 * 4];
    *(float4*)&ti[i4 * 4] = *(const float4*)&ki[i4 * 4];
  }
  if (tid < HID) { se2[tid] = e2[s * HID + tid]; sb[tid] = b1[s * HID + tid]; }
  __syncthreads();

  if (tid >= 250) return;
  const int lofs = 200 + 4 * tid;
  float so[4] = {0.f, 0.f, 0.f, 0.f};

  #pragma unroll
  for (int half = 0; half < 2; half++) {
    const int h0 = half * 5;
    float acc[5][4] = {};
    float we[8], wi[8];
    *(float4*)&we[4] = *(float4*)&se[lofs];
    *(float4*)&wi[4] = *(float4*)&si[lofs];
    for (int dstep = 0; dstep < 50; dstep++) {
      const int d0 = dstep * 4;
      *(float4*)&we[0] = *(float4*)&se[lofs - d0 - 4];
      *(float4*)&wi[0] = *(float4*)&si[lofs - d0 - 4];
      float4 tpe[5], tpi[5];
      #pragma unroll
      for (int h = 0; h < 5; h++) {
        tpe[h] = *(float4*)&te[(h0 + h) * TNO + d0];
        tpi[h] = *(float4*)&ti[(h0 + h) * TNO + d0];
      }
      #pragma unroll
      for (int dd = 0; dd < 4; dd++) {
        #pragma unroll
        for (int h = 0; h < 5; h++) {
          float tapeh = ((float*)&tpe[h])[dd];
          float tapih = ((float*)&tpi[h])[dd];
          #pragma unroll
          for (int j = 0; j < 4; j++) {
            acc[h][j] += tapeh * we[4 + j - dd];
            acc[h][j] += tapih * wi[4 + j - dd];
          }
        }
      }
      #pragma unroll
      for (int m = 0; m < 4; m++) { we[4 + m] = we[m]; wi[4 + m] = wi[m]; }
    }
    #pragma unroll
    for (int h = 0; h < 5; h++) {
      float eh = se2[h0 + h], bh = sb[h0 + h];
      #pragma unroll
      for (int j = 0; j < 4; j++) so[j] += eh * tanhf(acc[h][j] + bh);
    }
  }
  int t0 = cs + 4 * tid;
  *(float4*)&sub_bst[((long)b * SUB + s) * T_ + t0] = *(float4*)&so[0];
}

// ---------------- final: transpose sub_bst[b][s][t] -> sub_out[b][t][s], final[b][t] = sum_s + V_o
__global__ __launch_bounds__(256) void final_kernel(
    const float* __restrict__ sub_bst, const float* __restrict__ Vo,
    float* __restrict__ out_final, float* __restrict__ out_sub)
{
  int t = blockIdx.x * 256 + threadIdx.x;
  int b = blockIdx.y;
  if (t >= T_) return;
  float vo = Vo[0];
  float sum = 0.f;
  #pragma unroll
  for (int s = 0; s < SUB; s++) {
    float v = sub_bst[((long)b * SUB + s) * T_ + t];
    sum += v;
    out_sub[(((long)b * T_) + t) * SUB + s] = v;
  }
  out_final[(long)b * T_ + t] = sum + vo;
}

extern "C" void kernel_launch(void* const* d_in, const int* in_sizes, int n_in,
                              void* d_out, int out_size, void* d_ws, size_t ws_size,
                              hipStream_t stream)
{
  const float* S_e    = (const float*)d_in[0];
  const float* S_i    = (const float*)d_in[1];
  const int*   testp  = (const int*)d_in[3];
  const float* g_e    = (const float*)d_in[4];
  const float* g_i    = (const float*)d_in[5];
  const float* Es     = (const float*)d_in[6];
  const float* Is     = (const float*)d_in[7];
  const float* We     = (const float*)d_in[8];
  const float* Wi     = (const float*)d_in[9];
  const float* W2     = (const float*)d_in[10];
  const float* b1     = (const float*)d_in[11];
  const float* Ce_raw = (const float*)d_in[12];
  const float* Ci_raw = (const float*)d_in[13];
  const float* Vo     = (const float*)d_in[14];

  float* ws   = (float*)d_ws;
  float* CwE  = ws;                      // 40000
  float* CwI  = ws + 40000;              // 10000
  float* Keff = ws + 50000;              // 80000
  float* e2   = ws + 130000;             // 200
  float* synE = ws + 130200;             // 1,600,000
  float* synI = synE + 1600000;          // 1,600,000
  float* subb = synI + 1600000;          // 1,600,000

  float* out     = (float*)d_out;
  float* o_final = out;                  // 80,000
  float* o_sub   = out + 80000;          // 1,600,000
  float* o_Ce    = out + 1680000;        // 40,000
  float* o_Ci    = out + 1720000;        // 10,000

  prep1_kernel<<<11, 256, 0, stream>>>(Ce_raw, Ci_raw, g_e, g_i, Es, Is, W2, testp,
                                       o_Ce, o_Ci, CwE, CwI, e2);
  prep2_kernel<<<(2 * SUB * HID * TNO + 255) / 256, 256, 0, stream>>>(We, Wi, Keff);
  gemm_syn_kernel<<<dim3(T_ / 16, B_), 256, 0, stream>>>(S_e, S_i, CwE, CwI, synE, synI);
  conv_kernel<<<dim3(20, SUB, B_), 256, 0, stream>>>(synE, synI, Keff, e2, b1, subb);
  final_kernel<<<dim3((T_ + 255) / 256, B_), 256, 0, stream>>>(subb, Vo, o_final, o_sub);
}